// Round 3
// baseline (466.800 us; speedup 1.0000x reference)
//
#include <hip/hip_runtime.h>

typedef __bf16 bf16x8 __attribute__((ext_vector_type(8)));
typedef __bf16 bf16x4 __attribute__((ext_vector_type(4)));
typedef float  f32x4  __attribute__((ext_vector_type(4)));

#define LDS_XO 0        // x (bf16, [128][128]) then attn-out O [n][c]
#define LDS_Q  32768    // q [n][j] bf16
#define LDS_K  65536    // k [m][j] bf16
#define LDS_VT 98304    // v^T [d][m] bf16
#define LDS_P  131072   // per-wave P transpose buffer [16][128] bf16 x4 waves
#define LDS_TOTAL 147456

// XOR swizzle for 256B-row tiles: spreads 16B chunks of neighboring rows
// across banks so stride-256B column reads are conflict-free-ish.
__device__ __forceinline__ int swz(int row, int colb) {
    return row * 256 + (colb ^ ((row & 7) << 4));
}

__global__ void prep_weights(const float* __restrict__ qkv_w,
                             const float* __restrict__ proj_w,
                             __bf16* __restrict__ wq, __bf16* __restrict__ wp) {
    int i = blockIdx.x * 256 + threadIdx.x;           // grid covers 49152
    wq[i] = (__bf16)qkv_w[i];
    if (i < 16384) wp[i] = (__bf16)proj_w[i];
}

__global__ void __launch_bounds__(256, 1)
attn_fused(const float* __restrict__ x, const float* __restrict__ mask,
           const float* __restrict__ qkv_b, const float* __restrict__ proj_b,
           const __bf16* __restrict__ wq, const __bf16* __restrict__ wp,
           float* __restrict__ out) {
    extern __shared__ char smem[];
    const int b    = blockIdx.x;
    const int tid  = threadIdx.x;
    const int wave = tid >> 6;
    const int lane = tid & 63;
    const int l16  = lane & 15;
    const int lg   = lane >> 4;   // 0..3

    // ---------------- Phase A: x -> bf16 LDS (swizzled) ----------------
    {
        const float* xb = x + (size_t)b * 16384;
        #pragma unroll
        for (int it = 0; it < 8; ++it) {
            int i   = it * 256 + tid;
            int row = i >> 4;
            int c8  = (i & 15) << 3;
            float4 f0 = *(const float4*)(xb + row * 128 + c8);
            float4 f1 = *(const float4*)(xb + row * 128 + c8 + 4);
            bf16x8 v;
            v[0] = (__bf16)f0.x; v[1] = (__bf16)f0.y; v[2] = (__bf16)f0.z; v[3] = (__bf16)f0.w;
            v[4] = (__bf16)f1.x; v[5] = (__bf16)f1.y; v[6] = (__bf16)f1.z; v[7] = (__bf16)f1.w;
            *(bf16x8*)(smem + LDS_XO + swz(row, c8 * 2)) = v;
        }
    }
    __syncthreads();

    // ---------------- Phase B: QKV^T = W @ x^T  (swapped operands) -----
    // D[j][n]: lane holds 4 consecutive j (features) at fixed n.
    const int j0 = wave * 96;
    #pragma unroll
    for (int pass = 0; pass < 2; ++pass) {
        f32x4 acc[6][4];
        #pragma unroll
        for (int jt = 0; jt < 6; ++jt)
            #pragma unroll
            for (int nt = 0; nt < 4; ++nt)
                acc[jt][nt] = {0.f, 0.f, 0.f, 0.f};
        #pragma unroll
        for (int kc = 0; kc < 4; ++kc) {
            bf16x8 afr[6];
            #pragma unroll
            for (int jt = 0; jt < 6; ++jt)
                afr[jt] = *(const bf16x8*)(wq + (j0 + jt * 16 + l16) * 128 + kc * 32 + lg * 8);
            bf16x8 bfr[4];
            #pragma unroll
            for (int nt = 0; nt < 4; ++nt)
                bfr[nt] = *(const bf16x8*)(smem + LDS_XO +
                            swz((pass * 4 + nt) * 16 + l16, (kc * 32 + lg * 8) * 2));
            #pragma unroll
            for (int jt = 0; jt < 6; ++jt)
                #pragma unroll
                for (int nt = 0; nt < 4; ++nt)
                    acc[jt][nt] = __builtin_amdgcn_mfma_f32_16x16x32_bf16(
                                      afr[jt], bfr[nt], acc[jt][nt], 0, 0, 0);
        }
        // epilogue: +bias, write q/k as bf16x4 rows, v into v^T layout
        #pragma unroll
        for (int jt = 0; jt < 6; ++jt) {
            int jbase = j0 + jt * 16 + lg * 4;
            float4 bias = *(const float4*)(qkv_b + jbase);
            #pragma unroll
            for (int nt = 0; nt < 4; ++nt) {
                int n = (pass * 4 + nt) * 16 + l16;
                f32x4 a = acc[jt][nt];
                __bf16 e0 = (__bf16)(a[0] + bias.x);
                __bf16 e1 = (__bf16)(a[1] + bias.y);
                __bf16 e2 = (__bf16)(a[2] + bias.z);
                __bf16 e3 = (__bf16)(a[3] + bias.w);
                if (jbase < 128) {
                    bf16x4 v4 = {e0, e1, e2, e3};
                    *(bf16x4*)(smem + LDS_Q + swz(n, jbase * 2)) = v4;
                } else if (jbase < 256) {
                    bf16x4 v4 = {e0, e1, e2, e3};
                    *(bf16x4*)(smem + LDS_K + swz(n, (jbase - 128) * 2)) = v4;
                } else {
                    int d = jbase - 256;
                    *(__bf16*)(smem + LDS_VT + swz(d + 0, n * 2)) = e0;
                    *(__bf16*)(smem + LDS_VT + swz(d + 1, n * 2)) = e1;
                    *(__bf16*)(smem + LDS_VT + swz(d + 2, n * 2)) = e2;
                    *(__bf16*)(smem + LDS_VT + swz(d + 3, n * 2)) = e3;
                }
            }
        }
    }
    __syncthreads();

    // ---------------- Phase C: attention, one head per wave ------------
    const int h = wave;
    const float sc = 0.17677669529663687f;   // 1/sqrt(32)
    bf16x8 kfr[8];
    #pragma unroll
    for (int mt = 0; mt < 8; ++mt)
        kfr[mt] = *(const bf16x8*)(smem + LDS_K + swz(mt * 16 + l16, (h * 32 + lg * 8) * 2));
    bf16x8 vfr[2][4];
    #pragma unroll
    for (int dt = 0; dt < 2; ++dt)
        #pragma unroll
        for (int kc = 0; kc < 4; ++kc)
            vfr[dt][kc] = *(const bf16x8*)(smem + LDS_VT +
                            swz(h * 32 + dt * 16 + l16, (kc * 32 + lg * 8) * 2));

    const float* mwin = mask + (size_t)(b & 63) * 16384;
    char* pbase = smem + LDS_P + wave * 4096;

    for (int nt = 0; nt < 8; ++nt) {
        bf16x8 qfr = *(const bf16x8*)(smem + LDS_Q + swz(nt * 16 + l16, (h * 32 + lg * 8) * 2));
        f32x4 s[8];
        #pragma unroll
        for (int mt = 0; mt < 8; ++mt) {
            f32x4 z = {0.f, 0.f, 0.f, 0.f};
            s[mt] = __builtin_amdgcn_mfma_f32_16x16x32_bf16(qfr, kfr[mt], z, 0, 0, 0);
        }
        // scale + mask + row max
        float mx[4] = {-1e30f, -1e30f, -1e30f, -1e30f};
        #pragma unroll
        for (int mt = 0; mt < 8; ++mt)
            #pragma unroll
            for (int r = 0; r < 4; ++r) {
                float v = s[mt][r] * sc + mwin[(nt * 16 + lg * 4 + r) * 128 + mt * 16 + l16];
                s[mt][r] = v;
                mx[r] = fmaxf(mx[r], v);
            }
        #pragma unroll
        for (int r = 0; r < 4; ++r) {
            float m = mx[r];
            m = fmaxf(m, __shfl_xor(m, 1));
            m = fmaxf(m, __shfl_xor(m, 2));
            m = fmaxf(m, __shfl_xor(m, 4));
            m = fmaxf(m, __shfl_xor(m, 8));
            mx[r] = m;
        }
        float sm[4] = {0.f, 0.f, 0.f, 0.f};
        #pragma unroll
        for (int mt = 0; mt < 8; ++mt)
            #pragma unroll
            for (int r = 0; r < 4; ++r) {
                float p = __expf(s[mt][r] - mx[r]);
                s[mt][r] = p;
                sm[r] += p;
            }
        #pragma unroll
        for (int r = 0; r < 4; ++r) {
            float t = sm[r];
            t += __shfl_xor(t, 1);
            t += __shfl_xor(t, 2);
            t += __shfl_xor(t, 4);
            t += __shfl_xor(t, 8);
            sm[r] = 1.f / t;
        }
        // P -> per-wave LDS (bf16), transposing acc layout to A-frag layout
        #pragma unroll
        for (int mt = 0; mt < 8; ++mt)
            #pragma unroll
            for (int r = 0; r < 4; ++r)
                *(__bf16*)(pbase + swz(lg * 4 + r, (mt * 16 + l16) * 2)) =
                    (__bf16)(s[mt][r] * sm[r]);
        bf16x8 pafr[4];
        #pragma unroll
        for (int kc = 0; kc < 4; ++kc)
            pafr[kc] = *(const bf16x8*)(pbase + swz(l16, (kc * 32 + lg * 8) * 2));
        #pragma unroll
        for (int dt = 0; dt < 2; ++dt) {
            f32x4 o = {0.f, 0.f, 0.f, 0.f};
            #pragma unroll
            for (int kc = 0; kc < 4; ++kc)
                o = __builtin_amdgcn_mfma_f32_16x16x32_bf16(pafr[kc], vfr[dt][kc], o, 0, 0, 0);
            #pragma unroll
            for (int r = 0; r < 4; ++r)
                *(__bf16*)(smem + LDS_XO +
                    swz(nt * 16 + lg * 4 + r, (h * 32 + dt * 16 + l16) * 2)) = (__bf16)o[r];
        }
    }
    __syncthreads();

    // ---------------- Phase D: output projection -----------------------
    f32x4 facc[2][8];
    #pragma unroll
    for (int nt2 = 0; nt2 < 2; ++nt2)
        #pragma unroll
        for (int ct = 0; ct < 8; ++ct)
            facc[nt2][ct] = {0.f, 0.f, 0.f, 0.f};
    #pragma unroll
    for (int kc = 0; kc < 4; ++kc) {
        bf16x8 afr[2];
        #pragma unroll
        for (int nt2 = 0; nt2 < 2; ++nt2)
            afr[nt2] = *(const bf16x8*)(smem + LDS_XO +
                          swz((wave * 2 + nt2) * 16 + l16, (kc * 32 + lg * 8) * 2));
        bf16x8 bfr[8];
        #pragma unroll
        for (int ct = 0; ct < 8; ++ct)
            bfr[ct] = *(const bf16x8*)(wp + (ct * 16 + l16) * 128 + kc * 32 + lg * 8);
        #pragma unroll
        for (int nt2 = 0; nt2 < 2; ++nt2)
            #pragma unroll
            for (int ct = 0; ct < 8; ++ct)
                facc[nt2][ct] = __builtin_amdgcn_mfma_f32_16x16x32_bf16(
                                    afr[nt2], bfr[ct], facc[nt2][ct], 0, 0, 0);
    }
    float* ob = out + (size_t)b * 16384;
    #pragma unroll
    for (int ct = 0; ct < 8; ++ct) {
        float pb = proj_b[ct * 16 + l16];
        #pragma unroll
        for (int nt2 = 0; nt2 < 2; ++nt2) {
            int n0 = (wave * 2 + nt2) * 16 + lg * 4;
            #pragma unroll
            for (int r = 0; r < 4; ++r)
                ob[(n0 + r) * 128 + ct * 16 + l16] = facc[nt2][ct][r] + pb;
        }
    }
}

extern "C" void kernel_launch(void* const* d_in, const int* in_sizes, int n_in,
                              void* d_out, int out_size, void* d_ws, size_t ws_size,
                              hipStream_t stream) {
    const float* x      = (const float*)d_in[0];
    const float* mask   = (const float*)d_in[1];
    const float* qkv_w  = (const float*)d_in[2];
    const float* qkv_b  = (const float*)d_in[3];
    const float* proj_w = (const float*)d_in[4];
    const float* proj_b = (const float*)d_in[5];
    float* out = (float*)d_out;

    __bf16* wq = (__bf16*)d_ws;            // 384*128 bf16
    __bf16* wp = wq + 49152;               // 128*128 bf16

    prep_weights<<<192, 256, 0, stream>>>(qkv_w, proj_w, wq, wp);

    hipFuncSetAttribute((const void*)attn_fused,
                        hipFuncAttributeMaxDynamicSharedMemorySize, LDS_TOTAL);
    attn_fused<<<2048, 256, LDS_TOTAL, stream>>>(x, mask, qkv_b, proj_b, wq, wp, out);
}